// Round 6
// baseline (473.045 us; speedup 1.0000x reference)
//
#include <hip/hip_runtime.h>

// Problem constants
#define BB        16
#define HH        6
#define WW        4096
#define CC        128
#define TT        1024          // W/OVERLAP
#define NTOK      16384         // B*T
#define FIX       768           // H*C
#define HID       1024
#define CBK       1024
#define CBD       8
#define NPVQ      3
#define NRVQ      6
#define ZQ_SIZE   50331648ull   // B*H*W*C

// ws layout (byte offsets), all 16-aligned
#define OFF_ACC   0ull                            // 16 B loss accumulator (double)
#define OFF_EN64  16ull                           // 18*1024*8 f64 = 1179648 B
#define OFF_EN32  (OFF_EN64 + 1179648ull)         // 18*1024*8 f32 = 589824 B
#define OFF_PUT   (OFF_EN32 + 589824ull)          // 3*1024*8 f32  = 98304 B
#define OFF_R     (OFF_PUT + 98304ull)            // 3*16384*8 f64 = 3145728 B
#define OFF_ZQ    (OFF_R + 3145728ull)            // 3*16384*8 f32 = 1572864 B

// ---------------------------------------------------------------------------
// Kernel A1: l2-normalize all 18 codebooks -> fp64 table + fp32 mirror
// ---------------------------------------------------------------------------
__global__ __launch_bounds__(256) void knorm(const float* __restrict__ emb,
                                             double* __restrict__ en64,
                                             float* __restrict__ en32) {
    int gid = blockIdx.x * 256 + threadIdx.x;
    if (gid >= NPVQ * NRVQ * CBK) return;
    const float* e = emb + (size_t)gid * CBD;
    double v[CBD];
    double s = 0.0;
#pragma unroll
    for (int d = 0; d < CBD; ++d) { v[d] = (double)e[d]; s += v[d] * v[d]; }
    double n = fmax(sqrt(s), 1e-12);
#pragma unroll
    for (int d = 0; d < CBD; ++d) {
        double q = v[d] / n;
        en64[(size_t)gid * CBD + d] = q;
        en32[(size_t)gid * CBD + d] = (float)q;
    }
}

// ---------------------------------------------------------------------------
// Kernel A2: transpose pu[m][d][j] -> pu_t[m][j][d]  (96 KB, one-time)
// ---------------------------------------------------------------------------
__global__ __launch_bounds__(256) void kputr(const float* __restrict__ pu,
                                             float* __restrict__ pu_t) {
    int gid = blockIdx.x * 256 + threadIdx.x;        // coalesced read of pu
    if (gid >= NPVQ * CBD * HID) return;
    int j = gid & (HID - 1), md = gid >> 10;
    int m = md >> 3, d = md & 7;
    pu_t[((size_t)m * HID + j) * CBD + d] = pu[gid];
}

// ---------------------------------------------------------------------------
// Kernel B: gather 2 tokens (24 KB) into LDS, project 1024->8 (fp64).
// 384 thr = 6 waves: wave w -> token (w>=3), m = w%3. Per-(m,token) math is
// bit-identical to the R3 kernel (same j-order, same shuffle reduce).
// R5 BUG FIX: second-token index is g - 768*tk  (768 is NOT a power of two;
// `g & 767` scrambled the second token's LDS slice -> half the codes wrong).
// ---------------------------------------------------------------------------
__global__ __launch_bounds__(384) void kproj(const float* __restrict__ ze,
                                             const float* __restrict__ pd,
                                             double* __restrict__ r_ws) {
    __shared__ float x[2][NPVQ * HID];   // 24 KB
    const int tok0 = blockIdx.x * 2;
    const int b = tok0 >> 10, t0 = tok0 & 1023;
    const int tid = threadIdx.x;
    const size_t zbase = (size_t)b * (HH * WW * CC);
    // 1536 float4 total, 4 per thread; per (tk,h): 128 consecutive float4
#pragma unroll
    for (int q = 0; q < 4; ++q) {
        int g = tid + 384 * q;                 // [0,1536)
        int tk = g >= 768;
        int gg = g - tk * 768;                 // FIXED (was g & 767)
        int h = gg >> 7, v = gg & 127;
        const float4 val = *(const float4*)(ze + zbase + (size_t)(h * WW + (t0 + tk) * 4) * CC + v * 4);
        float vv[4] = {val.x, val.y, val.z, val.w};
#pragma unroll
        for (int e = 0; e < 4; ++e) {
            int oc = v * 4 + e, o = oc >> 7, c = oc & 127;
            x[tk][o * FIX + c * HH + h] = vv[e];
        }
    }
    __syncthreads();
    const int w = tid >> 6, l = tid & 63;
    const int tk = w >= 3, m = w - tk * 3;
    double acc[CBD] = {0, 0, 0, 0, 0, 0, 0, 0};
    for (int q = 0; q < 16; ++q) {
        int j = l + 64 * q;
        double xv = (double)x[tk][m * HID + j];
        const float* pr = pd + (size_t)(m * HID + j) * CBD;
#pragma unroll
        for (int d = 0; d < CBD; ++d) acc[d] = fma(xv, (double)pr[d], acc[d]);
    }
#pragma unroll
    for (int off = 32; off >= 1; off >>= 1) {
#pragma unroll
        for (int d = 0; d < CBD; ++d) acc[d] += __shfl_down(acc[d], off, 64);
    }
    if (l == 0) {
        double* rp = r_ws + ((size_t)m * NTOK + tok0 + tk) * CBD;
#pragma unroll
        for (int d = 0; d < CBD; ++d) rp[d] = acc[d];
    }
}

// ---------------------------------------------------------------------------
// Kernel C: residual VQ. fp32 certified scan + fp64 exact updates.
// Block = (m, 64-token group), 8 waves. Whole fp32 codebook (32 KB) staged
// per stream; wave w scans codes [w*128,(w+1)*128) tracking best+second.
// Cross-wave merge -> global top-1 + runner-up bound; if gap <= EPS the
// affected lanes rescan in fp64 from global (rare). Residual/loss fp64.
// ---------------------------------------------------------------------------
#define KV_WAVES   8
#define KV_THREADS (KV_WAVES * 64)
#define KV_WSLICE  (CBK / KV_WAVES)    // 128
#define KV_EPS     5e-6f               // >= 3.5x fp32 8-dot error bound (unit vectors)

__global__ __launch_bounds__(KV_THREADS) void kvq(const double* __restrict__ en_all,
                                                  const float* __restrict__ es_all,
                                                  const double* __restrict__ r_ws,
                                                  float* __restrict__ zq_ws,
                                                  float* __restrict__ out,     // d_out base
                                                  const int* __restrict__ nsp,
                                                  double* __restrict__ accum) {
    __shared__ __align__(16) float tbl[CBK * CBD];   // 32 KB
    __shared__ float mb1[KV_THREADS];                // 2 KB
    __shared__ float mb2[KV_THREADS];                // 2 KB
    __shared__ int   mbk[KV_THREADS];                // 2 KB

    const int blk = blockIdx.x;
    const int m = blk >> 8, g = blk & 255;
    const int tid = threadIdx.x;
    const int w = tid >> 6, l = tid & 63;
    const int tok = g * 64 + l;
    const int b = tok >> 10, t = tok & 1023;
    const int ns = *nsp;

    double r[CBD];
    {
        const double* rp = r_ws + ((size_t)m * NTOK + tok) * CBD;
#pragma unroll
        for (int d = 0; d < CBD; ++d) r[d] = rp[d];
    }
    double zq[CBD] = {0, 0, 0, 0, 0, 0, 0, 0};
    double loss = 0.0;

    const int kl0 = w * KV_WSLICE;
    for (int i = 0; i < ns; ++i) {
        const double* en = en_all + ((size_t)(m * NRVQ + i)) * CBK * CBD;
        const float*  es = es_all + ((size_t)(m * NRVQ + i)) * CBK * CBD;
        // rn = fp64-normalized residual, cast fp32 (scan is scale-invariant)
        double s = 0.0;
#pragma unroll
        for (int d = 0; d < CBD; ++d) s += r[d] * r[d];
        double inv = 1.0 / fmax(sqrt(s), 1e-12);
        float rn[CBD];
#pragma unroll
        for (int d = 0; d < CBD; ++d) rn[d] = (float)(r[d] * inv);

        __syncthreads();   // table free (prev stream fully scanned)
        {   // stage full fp32 codebook: 2048 float4, 4 per thread, coalesced
            const float4* src = (const float4*)es;
            float4* dst = (float4*)tbl;
#pragma unroll
            for (int q = 0; q < 4; ++q) dst[tid + KV_THREADS * q] = src[tid + KV_THREADS * q];
        }
        __syncthreads();   // table ready

        float b1 = -1e30f, b2 = -1e30f;
        int bk = kl0;
        for (int k = kl0; k < kl0 + KV_WSLICE; k += 4) {
            float dots[4];
#pragma unroll
            for (int u = 0; u < 4; ++u) {
                const float* ev = tbl + (size_t)(k + u) * CBD;
                float a0 = 0.0f, a1 = 0.0f;
#pragma unroll
                for (int d = 0; d < CBD; d += 2) {
                    a0 = fmaf(rn[d], ev[d], a0);
                    a1 = fmaf(rn[d + 1], ev[d + 1], a1);
                }
                dots[u] = a0 + a1;
            }
#pragma unroll
            for (int u = 0; u < 4; ++u) {
                float dv = dots[u];
                if (dv > b1) { b2 = b1; b1 = dv; bk = k + u; }   // strict >: first max
                else if (dv > b2) { b2 = dv; }
            }
        }
        mb1[tid] = b1; mb2[tid] = b2; mbk[tid] = bk;
        __syncthreads();
        // 8-way top-2 merge (slices ascending in w -> strict > keeps first max)
        float B1 = mb1[l], B2 = mb2[l];
        int K = mbk[l];
#pragma unroll
        for (int w2 = 1; w2 < KV_WAVES; ++w2) {
            float c1 = mb1[w2 * 64 + l];
            float c2 = mb2[w2 * 64 + l];
            int   ck = mbk[w2 * 64 + l];
            if (c1 > B1) { B2 = fmaxf(B1, c2); B1 = c1; K = ck; }
            else         { B2 = fmaxf(B2, c1); }
        }
        int bbk = K;
        // certification: fp32 gap > EPS  =>  fp32 winner == fp64 argmax
        bool uncert = (B1 - B2) <= KV_EPS;
        if (__any(uncert)) {
            if (uncert) {   // exact fp64 rescan (rare; argmax invariant to scale)
                double best = -1e300;
                int kk = 0;
                for (int k = 0; k < CBK; ++k) {
                    const double* ev = en + (size_t)k * CBD;
                    double a0 = 0.0, a1 = 0.0;
#pragma unroll
                    for (int d = 0; d < CBD; d += 2) {
                        a0 = fma(r[d], ev[d], a0);
                        a1 = fma(r[d + 1], ev[d + 1], a1);
                    }
                    double dot = a0 + a1;
                    if (dot > best) { best = dot; kk = k; }
                }
                bbk = kk;
            }
        }
        // winner vector in fp64 (L2-resident), exact residual/loss updates
        const double* qv = en + (size_t)bbk * CBD;
        if (w == 0) {
            double ls = 0.0;
#pragma unroll
            for (int d = 0; d < CBD; ++d) { double df = qv[d] - r[d]; ls += df * df; }
            loss += ls;
            out[ZQ_SIZE + ((size_t)(b * ns + i) * NPVQ + m) * TT + t] = (float)bbk;
        }
#pragma unroll
        for (int d = 0; d < CBD; ++d) { double q = qv[d]; r[d] -= q; zq[d] += q; }
    }

    if (w == 0) {
        float* zp = zq_ws + ((size_t)m * NTOK + tok) * CBD;
#pragma unroll
        for (int d = 0; d < CBD; ++d) zp[d] = (float)zq[d];
#pragma unroll
        for (int off = 32; off >= 1; off >>= 1) loss += __shfl_down(loss, off, 64);
        if (l == 0) atomicAdd(accum, loss);
    }
}

// ---------------------------------------------------------------------------
// Kernel D: up-projection 8->1024 + inverse permutation scatter (coalesced),
// plus loss epilogue. Block = 32 consecutive tokens. pu_t gives contiguous
// 8-float weight rows (2 x b128 per (m,j)); same values/fmaf order as R3.
// ---------------------------------------------------------------------------
__global__ __launch_bounds__(256) void kout(const float* __restrict__ pu_t,
                                            const float* __restrict__ zq_ws,
                                            float* __restrict__ out,
                                            const int* __restrict__ nsp,
                                            const double* __restrict__ accum) {
    __shared__ float zl[32][NPVQ][CBD];   // 3 KB
    const int blk = blockIdx.x;
    const int tok0 = blk * 32;
    const int b = tok0 >> 10, t0 = tok0 & 1023;
    const int tid = threadIdx.x;
#pragma unroll
    for (int q = 0; q < 3; ++q) {
        int ii = tid + 256 * q;            // [0,768)
        int mm = ii >> 8, rem = ii & 255, tt = rem >> 3, d = rem & 7;
        zl[tt][mm][d] = zq_ws[((size_t)mm * NTOK + tok0 + tt) * CBD + d];
    }
    __syncthreads();
    const size_t obase = (size_t)b * (HH * WW * CC);
#pragma unroll 2
    for (int q = 0; q < 12; ++q) {
        int idx = tid + 256 * q;           // (h,o,c) linear
        int h = idx >> 9, rem = idx & 511, o = rem >> 7, c = rem & 127;
        int f = o * FIX + c * HH + h;
        int m = f >> 10, j = f & 1023;
        const float4* p4 = (const float4*)(pu_t + ((size_t)m * HID + j) * CBD);
        float4 pa = p4[0], pb = p4[1];
        float pu8[CBD] = {pa.x, pa.y, pa.z, pa.w, pb.x, pb.y, pb.z, pb.w};
        size_t rowbase = obase + ((size_t)h * WW + t0 * 4 + o) * CC + c;
        for (int tt = 0; tt < 32; ++tt) {
            float y = 0.0f;
#pragma unroll
            for (int d = 0; d < CBD; ++d) y = fmaf(zl[tt][m][d], pu8[d], y);
            out[rowbase + (size_t)tt * 4 * CC] = y;
        }
    }
    if (blk == 0 && tid == 0) {
        int ns = *nsp;
        double s = *accum;
        float lv = (float)(s / (double)(NTOK * CBD * NPVQ));
        size_t lbase = ZQ_SIZE + (size_t)BB * ns * NPVQ * TT;
        out[lbase] = lv;       // cb_loss / 3
        out[lbase + 1] = lv;   // cm_loss / 3 (numerically identical)
    }
}

// ---------------------------------------------------------------------------
extern "C" void kernel_launch(void* const* d_in, const int* in_sizes, int n_in,
                              void* d_out, int out_size, void* d_ws, size_t ws_size,
                              hipStream_t stream) {
    const float* ze  = (const float*)d_in[0];
    const float* emb = (const float*)d_in[1];
    const float* pd  = (const float*)d_in[2];
    const float* pu  = (const float*)d_in[3];
    const int*   nsp = (const int*)d_in[4];
    float* out = (float*)d_out;
    char* ws = (char*)d_ws;

    double* accum = (double*)(ws + OFF_ACC);
    double* en64  = (double*)(ws + OFF_EN64);
    float*  en32  = (float*)(ws + OFF_EN32);
    float*  pu_t  = (float*)(ws + OFF_PUT);
    double* r_ws  = (double*)(ws + OFF_R);
    float*  zq_ws = (float*)(ws + OFF_ZQ);

    hipMemsetAsync(accum, 0, 16, stream);
    knorm<<<(NPVQ * NRVQ * CBK + 255) / 256, 256, 0, stream>>>(emb, en64, en32);
    kputr<<<(NPVQ * CBD * HID + 255) / 256, 256, 0, stream>>>(pu, pu_t);
    kproj<<<NTOK / 2, 384, 0, stream>>>(ze, pd, r_ws);
    kvq<<<NPVQ * (NTOK / 64), KV_THREADS, 0, stream>>>(en64, en32, r_ws, zq_ws, out, nsp, accum);
    kout<<<NTOK / 32, 256, 0, stream>>>(pu_t, zq_ws, out, nsp, accum);
}

// Round 7
// 330.005 us; speedup vs baseline: 1.4335x; 1.4335x over previous
//
#include <hip/hip_runtime.h>

// Problem constants
#define BB        16
#define HH        6
#define WW        4096
#define CC        128
#define TT        1024          // W/OVERLAP
#define NTOK      16384         // B*T
#define FIX       768           // H*C
#define HID       1024
#define CBK       1024
#define CBD       8
#define NPVQ      3
#define NRVQ      6
#define ZQ_SIZE   50331648ull   // B*H*W*C

// ws layout (byte offsets), all 16-aligned
#define OFF_ACC   0ull                            // 16 B loss accumulator (double)
#define OFF_EN64  16ull                           // 18*1024*8 f64 = 1179648 B
#define OFF_EN32  (OFF_EN64 + 1179648ull)         // 18*1024*8 f32 = 589824 B
#define OFF_PUT   (OFF_EN32 + 589824ull)          // 3*1024*8 f32  = 98304 B
#define OFF_R     (OFF_PUT + 98304ull)            // 3*16384*8 f64 = 3145728 B
#define OFF_ZQ    (OFF_R + 3145728ull)            // 3*16384*8 f32 = 1572864 B

// ---------------------------------------------------------------------------
// Kernel A1: l2-normalize all 18 codebooks -> fp64 table + fp32 mirror
// ---------------------------------------------------------------------------
__global__ __launch_bounds__(256) void knorm(const float* __restrict__ emb,
                                             double* __restrict__ en64,
                                             float* __restrict__ en32) {
    int gid = blockIdx.x * 256 + threadIdx.x;
    if (gid >= NPVQ * NRVQ * CBK) return;
    const float* e = emb + (size_t)gid * CBD;
    double v[CBD];
    double s = 0.0;
#pragma unroll
    for (int d = 0; d < CBD; ++d) { v[d] = (double)e[d]; s += v[d] * v[d]; }
    double n = fmax(sqrt(s), 1e-12);
#pragma unroll
    for (int d = 0; d < CBD; ++d) {
        double q = v[d] / n;
        en64[(size_t)gid * CBD + d] = q;
        en32[(size_t)gid * CBD + d] = (float)q;
    }
}

// ---------------------------------------------------------------------------
// Kernel A2: transpose pu[m][d][j] -> pu_t[m][j][d]  (96 KB, one-time)
// ---------------------------------------------------------------------------
__global__ __launch_bounds__(256) void kputr(const float* __restrict__ pu,
                                             float* __restrict__ pu_t) {
    int gid = blockIdx.x * 256 + threadIdx.x;        // coalesced read of pu
    if (gid >= NPVQ * CBD * HID) return;
    int j = gid & (HID - 1), md = gid >> 10;
    int m = md >> 3, d = md & 7;
    pu_t[((size_t)m * HID + j) * CBD + d] = pu[gid];
}

// ---------------------------------------------------------------------------
// Kernel B: gather 2 tokens (24 KB) into LDS, project 1024->8 (fp64).
// 384 thr = 6 waves: wave w -> token (w>=3), m = w%3. (R5 index fix kept.)
// ---------------------------------------------------------------------------
__global__ __launch_bounds__(384) void kproj(const float* __restrict__ ze,
                                             const float* __restrict__ pd,
                                             double* __restrict__ r_ws) {
    __shared__ float x[2][NPVQ * HID];   // 24 KB
    const int tok0 = blockIdx.x * 2;
    const int b = tok0 >> 10, t0 = tok0 & 1023;
    const int tid = threadIdx.x;
    const size_t zbase = (size_t)b * (HH * WW * CC);
#pragma unroll
    for (int q = 0; q < 4; ++q) {
        int g = tid + 384 * q;                 // [0,1536)
        int tk = g >= 768;
        int gg = g - tk * 768;                 // (768 not pow2 — no masking!)
        int h = gg >> 7, v = gg & 127;
        const float4 val = *(const float4*)(ze + zbase + (size_t)(h * WW + (t0 + tk) * 4) * CC + v * 4);
        float vv[4] = {val.x, val.y, val.z, val.w};
#pragma unroll
        for (int e = 0; e < 4; ++e) {
            int oc = v * 4 + e, o = oc >> 7, c = oc & 127;
            x[tk][o * FIX + c * HH + h] = vv[e];
        }
    }
    __syncthreads();
    const int w = tid >> 6, l = tid & 63;
    const int tk = w >= 3, m = w - tk * 3;
    double acc[CBD] = {0, 0, 0, 0, 0, 0, 0, 0};
    for (int q = 0; q < 16; ++q) {
        int j = l + 64 * q;
        double xv = (double)x[tk][m * HID + j];
        const float* pr = pd + (size_t)(m * HID + j) * CBD;
#pragma unroll
        for (int d = 0; d < CBD; ++d) acc[d] = fma(xv, (double)pr[d], acc[d]);
    }
#pragma unroll
    for (int off = 32; off >= 1; off >>= 1) {
#pragma unroll
        for (int d = 0; d < CBD; ++d) acc[d] += __shfl_down(acc[d], off, 64);
    }
    if (l == 0) {
        double* rp = r_ws + ((size_t)m * NTOK + tok0 + tk) * CBD;
#pragma unroll
        for (int d = 0; d < CBD; ++d) rp[d] = acc[d];
    }
}

// ---------------------------------------------------------------------------
// Kernel C: residual VQ. fp32 certified scan + TARGETED fp64 re-certification.
// Block = (m, 64-token group), 8 waves. Whole fp32 codebook (32 KB) in LDS
// per stream; wave w scans codes [w*128,(w+1)*128) tracking best+second.
// Cross-wave merge -> global top-1/runner-up. If gap <= EPS (rare), an extra
// UNIFORM-BRANCH phase re-walks the LDS slice, computes fp64 dots from global
// only for codes within EPS_CAND of B1 (lane-divergent vector loads, no
// s_load serialization), and re-merges with (value, min-index) order.
// Residual/loss updates in fp64 — decision-identical to the R3 pipeline.
// ---------------------------------------------------------------------------
#define KV_WAVES    8
#define KV_THREADS  (KV_WAVES * 64)
#define KV_WSLICE   (CBK / KV_WAVES)   // 128
#define KV_EPS      2e-6f              // cert gap  (> 2x fp32 8-dot err bound)
#define KV_EPS_CAND 2e-6f              // candidate window (same 2e bound)

__global__ __launch_bounds__(KV_THREADS) void kvq(const double* __restrict__ en_all,
                                                  const float* __restrict__ es_all,
                                                  const double* __restrict__ r_ws,
                                                  float* __restrict__ zq_ws,
                                                  float* __restrict__ out,     // d_out base
                                                  const int* __restrict__ nsp,
                                                  double* __restrict__ accum) {
    __shared__ __align__(16) float tbl[CBK * CBD];   // 32 KB
    __shared__ float  mb1[KV_THREADS];               // 2 KB
    __shared__ float  mb2[KV_THREADS];               // 2 KB
    __shared__ int    mbk[KV_THREADS];               // 2 KB
    __shared__ double md64[KV_THREADS];              // 4 KB (recert merge)
    __shared__ int    mk64[KV_THREADS];              // 2 KB (recert merge)

    const int blk = blockIdx.x;
    const int m = blk >> 8, g = blk & 255;
    const int tid = threadIdx.x;
    const int w = tid >> 6, l = tid & 63;
    const int tok = g * 64 + l;
    const int b = tok >> 10, t = tok & 1023;
    const int ns = *nsp;

    double r[CBD];
    {
        const double* rp = r_ws + ((size_t)m * NTOK + tok) * CBD;
#pragma unroll
        for (int d = 0; d < CBD; ++d) r[d] = rp[d];
    }
    double zq[CBD] = {0, 0, 0, 0, 0, 0, 0, 0};
    double loss = 0.0;

    const int kl0 = w * KV_WSLICE;
    for (int i = 0; i < ns; ++i) {
        const double* en = en_all + ((size_t)(m * NRVQ + i)) * CBK * CBD;
        const float*  es = es_all + ((size_t)(m * NRVQ + i)) * CBK * CBD;
        // rn = fp64-normalized residual, cast fp32 (scan is scale-invariant)
        double s = 0.0;
#pragma unroll
        for (int d = 0; d < CBD; ++d) s += r[d] * r[d];
        double inv = 1.0 / fmax(sqrt(s), 1e-12);
        float rn[CBD];
#pragma unroll
        for (int d = 0; d < CBD; ++d) rn[d] = (float)(r[d] * inv);

        __syncthreads();   // table free (prev stream fully scanned)
        {   // stage full fp32 codebook: 2048 float4, 4 per thread, coalesced
            const float4* src = (const float4*)es;
            float4* dst = (float4*)tbl;
#pragma unroll
            for (int q = 0; q < 4; ++q) dst[tid + KV_THREADS * q] = src[tid + KV_THREADS * q];
        }
        __syncthreads();   // table ready

        float b1 = -1e30f, b2 = -1e30f;
        int bk = kl0;
        for (int k = kl0; k < kl0 + KV_WSLICE; k += 4) {
            float dots[4];
#pragma unroll
            for (int u = 0; u < 4; ++u) {
                const float* ev = tbl + (size_t)(k + u) * CBD;
                float a0 = 0.0f, a1 = 0.0f;
#pragma unroll
                for (int d = 0; d < CBD; d += 2) {
                    a0 = fmaf(rn[d], ev[d], a0);
                    a1 = fmaf(rn[d + 1], ev[d + 1], a1);
                }
                dots[u] = a0 + a1;
            }
#pragma unroll
            for (int u = 0; u < 4; ++u) {
                float dv = dots[u];
                if (dv > b1) { b2 = b1; b1 = dv; bk = k + u; }   // strict >: first max
                else if (dv > b2) { b2 = dv; }
            }
        }
        mb1[tid] = b1; mb2[tid] = b2; mbk[tid] = bk;
        __syncthreads();
        // 8-way top-2 merge (slices ascending in w -> strict > keeps first max)
        float B1 = mb1[l], B2 = mb2[l];
        int K = mbk[l];
#pragma unroll
        for (int w2 = 1; w2 < KV_WAVES; ++w2) {
            float c1 = mb1[w2 * 64 + l];
            float c2 = mb2[w2 * 64 + l];
            int   ck = mbk[w2 * 64 + l];
            if (c1 > B1) { B2 = fmaxf(B1, c2); B1 = c1; K = ck; }
            else         { B2 = fmaxf(B2, c1); }
        }
        int bbk = K;
        // certification: fp32 gap > EPS  =>  fp32 winner == fp64 argmax.
        // uncert is computed identically in every wave (same LDS inputs)
        // => __any(uncert) is block-uniform => conditional barriers are safe.
        bool uncert = (B1 - B2) <= KV_EPS;
        if (__any(uncert)) {
            __syncthreads();   // all waves done reading mbk from the merge
            double rb = -1e300;
            int rk = CBK;      // sentinel (larger than any real index)
            for (int k = kl0; k < kl0 + KV_WSLICE; ++k) {
                // recompute dot32 EXACTLY as the scan (same op order)
                const float* ev = tbl + (size_t)k * CBD;
                float a0 = 0.0f, a1 = 0.0f;
#pragma unroll
                for (int d = 0; d < CBD; d += 2) {
                    a0 = fmaf(rn[d], ev[d], a0);
                    a1 = fmaf(rn[d + 1], ev[d + 1], a1);
                }
                float dv = a0 + a1;
                if (uncert && dv >= B1 - KV_EPS_CAND) {
                    // candidate: exact fp64 dot (lane-divergent global load)
                    const double* e64 = en + (size_t)k * CBD;
                    double q0 = 0.0, q1 = 0.0;
#pragma unroll
                    for (int d = 0; d < CBD; d += 2) {
                        q0 = fma(r[d], e64[d], q0);
                        q1 = fma(r[d + 1], e64[d + 1], q1);
                    }
                    double dot = q0 + q1;
                    if (dot > rb || (dot == rb && k < rk)) { rb = dot; rk = k; }
                }
            }
            md64[tid] = rb; mk64[tid] = rk;
            __syncthreads();
            if (uncert) {
                double R = md64[l];
                int RK = mk64[l];
#pragma unroll
                for (int w2 = 1; w2 < KV_WAVES; ++w2) {
                    double d2 = md64[w2 * 64 + l];
                    int    k2 = mk64[w2 * 64 + l];
                    if (d2 > R || (d2 == R && k2 < RK)) { R = d2; RK = k2; }
                }
                bbk = RK;
            }
        }
        // winner vector in fp64 (L2-resident), exact residual/loss updates
        const double* qv = en + (size_t)bbk * CBD;
        if (w == 0) {
            double ls = 0.0;
#pragma unroll
            for (int d = 0; d < CBD; ++d) { double df = qv[d] - r[d]; ls += df * df; }
            loss += ls;
            out[ZQ_SIZE + ((size_t)(b * ns + i) * NPVQ + m) * TT + t] = (float)bbk;
        }
#pragma unroll
        for (int d = 0; d < CBD; ++d) { double q = qv[d]; r[d] -= q; zq[d] += q; }
    }

    if (w == 0) {
        float* zp = zq_ws + ((size_t)m * NTOK + tok) * CBD;
#pragma unroll
        for (int d = 0; d < CBD; ++d) zp[d] = (float)zq[d];
#pragma unroll
        for (int off = 32; off >= 1; off >>= 1) loss += __shfl_down(loss, off, 64);
        if (l == 0) atomicAdd(accum, loss);
    }
}

// ---------------------------------------------------------------------------
// Kernel D: up-projection 8->1024 + inverse permutation scatter (coalesced),
// plus loss epilogue. Block = 32 consecutive tokens.
// ---------------------------------------------------------------------------
__global__ __launch_bounds__(256) void kout(const float* __restrict__ pu_t,
                                            const float* __restrict__ zq_ws,
                                            float* __restrict__ out,
                                            const int* __restrict__ nsp,
                                            const double* __restrict__ accum) {
    __shared__ float zl[32][NPVQ][CBD];   // 3 KB
    const int blk = blockIdx.x;
    const int tok0 = blk * 32;
    const int b = tok0 >> 10, t0 = tok0 & 1023;
    const int tid = threadIdx.x;
#pragma unroll
    for (int q = 0; q < 3; ++q) {
        int ii = tid + 256 * q;            // [0,768)
        int mm = ii >> 8, rem = ii & 255, tt = rem >> 3, d = rem & 7;
        zl[tt][mm][d] = zq_ws[((size_t)mm * NTOK + tok0 + tt) * CBD + d];
    }
    __syncthreads();
    const size_t obase = (size_t)b * (HH * WW * CC);
#pragma unroll 2
    for (int q = 0; q < 12; ++q) {
        int idx = tid + 256 * q;           // (h,o,c) linear
        int h = idx >> 9, rem = idx & 511, o = rem >> 7, c = rem & 127;
        int f = o * FIX + c * HH + h;
        int m = f >> 10, j = f & 1023;
        const float4* p4 = (const float4*)(pu_t + ((size_t)m * HID + j) * CBD);
        float4 pa = p4[0], pb = p4[1];
        float pu8[CBD] = {pa.x, pa.y, pa.z, pa.w, pb.x, pb.y, pb.z, pb.w};
        size_t rowbase = obase + ((size_t)h * WW + t0 * 4 + o) * CC + c;
        for (int tt = 0; tt < 32; ++tt) {
            float y = 0.0f;
#pragma unroll
            for (int d = 0; d < CBD; ++d) y = fmaf(zl[tt][m][d], pu8[d], y);
            out[rowbase + (size_t)tt * 4 * CC] = y;
        }
    }
    if (blk == 0 && tid == 0) {
        int ns = *nsp;
        double s = *accum;
        float lv = (float)(s / (double)(NTOK * CBD * NPVQ));
        size_t lbase = ZQ_SIZE + (size_t)BB * ns * NPVQ * TT;
        out[lbase] = lv;       // cb_loss / 3
        out[lbase + 1] = lv;   // cm_loss / 3 (numerically identical)
    }
}

// ---------------------------------------------------------------------------
extern "C" void kernel_launch(void* const* d_in, const int* in_sizes, int n_in,
                              void* d_out, int out_size, void* d_ws, size_t ws_size,
                              hipStream_t stream) {
    const float* ze  = (const float*)d_in[0];
    const float* emb = (const float*)d_in[1];
    const float* pd  = (const float*)d_in[2];
    const float* pu  = (const float*)d_in[3];
    const int*   nsp = (const int*)d_in[4];
    float* out = (float*)d_out;
    char* ws = (char*)d_ws;

    double* accum = (double*)(ws + OFF_ACC);
    double* en64  = (double*)(ws + OFF_EN64);
    float*  en32  = (float*)(ws + OFF_EN32);
    float*  pu_t  = (float*)(ws + OFF_PUT);
    double* r_ws  = (double*)(ws + OFF_R);
    float*  zq_ws = (float*)(ws + OFF_ZQ);

    hipMemsetAsync(accum, 0, 16, stream);
    knorm<<<(NPVQ * NRVQ * CBK + 255) / 256, 256, 0, stream>>>(emb, en64, en32);
    kputr<<<(NPVQ * CBD * HID + 255) / 256, 256, 0, stream>>>(pu, pu_t);
    kproj<<<NTOK / 2, 384, 0, stream>>>(ze, pd, r_ws);
    kvq<<<NPVQ * (NTOK / 64), KV_THREADS, 0, stream>>>(en64, en32, r_ws, zq_ws, out, nsp, accum);
    kout<<<NTOK / 32, 256, 0, stream>>>(pu_t, zq_ws, out, nsp, accum);
}